// Round 1
// baseline (133.596 us; speedup 1.0000x reference)
//
#include <hip/hip_runtime.h>
#include <math.h>

namespace {

constexpr int NG     = 2048;
constexpr int IMG_H  = 160;
constexpr int IMG_W  = 224;
constexpr int HW     = IMG_H * IMG_W;   // 35840
constexpr int SEG    = 8;
constexpr int SEGLEN = NG / SEG;        // 256
constexpr int PIXBLK = 256;
constexpr int NPIXBLK = HW / PIXBLK;    // 140

constexpr float TFX   = 0.5774f;
constexpr float TFY   = (float)(0.5774 * 160.0 / 224.0);
constexpr float FXC   = (float)(224.0 / (2.0 * 0.5774));
constexpr float FYC   = (float)(160.0 / (2.0 * (0.5774 * 160.0 / 224.0)));
constexpr float LIMX  = (float)(1.3 * 0.5774);
constexpr float LIMY  = (float)(1.3 * (0.5774 * 160.0 / 224.0));
constexpr float A_MIN = (float)(1.0 / 255.0);
constexpr float NEAR  = 0.2f;
constexpr float LOWPASS = 0.3f;

// output float offsets (flat, in return order)
constexpr int O_COLOR = 0;
constexpr int O_RADII = 3 * HW;           // 107520
constexpr int O_DEPTH = O_RADII + NG;     // 109568
constexpr int O_OPAC  = O_DEPTH + HW;     // 145408
constexpr int O_NT    = O_OPAC + HW;      // 181248

// workspace float offsets
// unsorted fields: 10 arrays of NG: 0 px,1 py,2 c0,3 c1,4 c2,5 op,6 r,7 g,8 b,9 dep
constexpr int W_U    = 0;
constexpr int W_KEY  = 10 * NG;
constexpr int W_S    = 11 * NG;   // sorted fields, same 10-array layout
constexpr int W_ORG  = 21 * NG;   // int: original index per sorted slot
constexpr int W_NT   = 22 * NG;   // int: per-gaussian touch counters
constexpr int W_PART = 23 * NG;   // 5 * SEG * HW floats: T, Sc0, Sc1, Sc2, Sd

} // namespace

__global__ void k_pre(const float* __restrict__ means3D,
                      const float* __restrict__ opac,
                      const float* __restrict__ cols,
                      const float* __restrict__ scales,
                      const float* __restrict__ rots,
                      const float* __restrict__ vm,
                      float* __restrict__ wsf,
                      int* __restrict__ ntouch,
                      float* __restrict__ out)
{
    int i = blockIdx.x * blockDim.x + threadIdx.x;
    if (i >= NG) return;
    ntouch[i] = 0;

    float R00 = vm[0], R01 = vm[1], R02 = vm[2],  T0 = vm[3];
    float R10 = vm[4], R11 = vm[5], R12 = vm[6],  T1 = vm[7];
    float R20 = vm[8], R21 = vm[9], R22 = vm[10], T2 = vm[11];

    float mx = means3D[3*i], my = means3D[3*i+1], mz = means3D[3*i+2];
    float tx = R00*mx + R01*my + R02*mz + T0;
    float ty = R10*mx + R11*my + R12*mz + T1;
    float tz = R20*mx + R21*my + R22*mz + T2;

    float txz = fminf(LIMX, fmaxf(-LIMX, tx / tz)) * tz;
    float tyz = fminf(LIMY, fmaxf(-LIMY, ty / tz)) * tz;

    // quaternion (w,x,y,z) -> rotation
    float qw = rots[4*i], qx = rots[4*i+1], qy = rots[4*i+2], qz = rots[4*i+3];
    float qn = 1.0f / sqrtf(qw*qw + qx*qx + qy*qy + qz*qz);
    qw *= qn; qx *= qn; qy *= qn; qz *= qn;
    float r00 = 1.0f - 2.0f*(qy*qy + qz*qz), r01 = 2.0f*(qx*qy - qw*qz), r02 = 2.0f*(qx*qz + qw*qy);
    float r10 = 2.0f*(qx*qy + qw*qz), r11 = 1.0f - 2.0f*(qx*qx + qz*qz), r12 = 2.0f*(qy*qz - qw*qx);
    float r20 = 2.0f*(qx*qz - qw*qy), r21 = 2.0f*(qy*qz + qw*qx), r22 = 1.0f - 2.0f*(qx*qx + qy*qy);

    float s0 = scales[3*i];   s0 = s0 * s0;   // SCALE_MOD = 1
    float s1 = scales[3*i+1]; s1 = s1 * s1;
    float s2 = scales[3*i+2]; s2 = s2 * s2;

    // Sigma = R diag(s) R^T
    float S00 = r00*r00*s0 + r01*r01*s1 + r02*r02*s2;
    float S01 = r00*r10*s0 + r01*r11*s1 + r02*r12*s2;
    float S02 = r00*r20*s0 + r01*r21*s1 + r02*r22*s2;
    float S11 = r10*r10*s0 + r11*r11*s1 + r12*r12*s2;
    float S12 = r10*r20*s0 + r11*r21*s1 + r12*r22*s2;
    float S22 = r20*r20*s0 + r21*r21*s1 + r22*r22*s2;

    float j00 = FXC / tz;
    float j02 = -FXC * txz / (tz * tz);
    float j11 = FYC / tz;
    float j12 = -FYC * tyz / (tz * tz);

    // Tm = J @ Rw  (2x3)
    float Tm00 = j00*R00 + j02*R20, Tm01 = j00*R01 + j02*R21, Tm02 = j00*R02 + j02*R22;
    float Tm10 = j11*R10 + j12*R20, Tm11 = j11*R11 + j12*R21, Tm12 = j11*R12 + j12*R22;

    // M = Tm @ Sigma (2x3)
    float M00 = Tm00*S00 + Tm01*S01 + Tm02*S02;
    float M01 = Tm00*S01 + Tm01*S11 + Tm02*S12;
    float M02 = Tm00*S02 + Tm01*S12 + Tm02*S22;
    float M10 = Tm10*S00 + Tm11*S01 + Tm12*S02;
    float M11 = Tm10*S01 + Tm11*S11 + Tm12*S12;
    float M12 = Tm10*S02 + Tm11*S12 + Tm12*S22;

    float cov00 = M00*Tm00 + M01*Tm01 + M02*Tm02;
    float cov01 = M00*Tm10 + M01*Tm11 + M02*Tm12;
    float cov11 = M10*Tm10 + M11*Tm11 + M12*Tm12;

    float a = cov00 + LOWPASS;
    float b = cov01;
    float c = cov11 + LOWPASS;
    float det = a*c - b*b;
    float dinv = 1.0f / det;
    float con0 = c * dinv, con1 = -b * dinv, con2 = a * dinv;

    float mid  = 0.5f * (a + c);
    float lam1 = mid + sqrtf(fmaxf(0.1f, mid*mid - det));
    float radf = ceilf(3.0f * sqrtf(lam1));

    float px = ((tx / (tz * TFX) + 1.0f) * (float)IMG_W - 1.0f) * 0.5f;
    float py = ((ty / (tz * TFY) + 1.0f) * (float)IMG_H - 1.0f) * 0.5f;

    bool valid = (tz > NEAR) && (det > 0.0f) && (radf > 0.0f);

    float vpx = valid ? px : 0.0f;
    float vpy = valid ? py : 0.0f;
    float v0  = valid ? con0 : 0.0f;
    float v1  = valid ? con1 : 0.0f;
    float v2  = valid ? con2 : 0.0f;
    float vop = valid ? opac[i] : 0.0f;
    float vr  = valid ? cols[3*i]   : 0.0f;
    float vg  = valid ? cols[3*i+1] : 0.0f;
    float vb  = valid ? cols[3*i+2] : 0.0f;
    float vd  = valid ? tz : 0.0f;

    wsf[W_U + 0*NG + i] = vpx;
    wsf[W_U + 1*NG + i] = vpy;
    wsf[W_U + 2*NG + i] = v0;
    wsf[W_U + 3*NG + i] = v1;
    wsf[W_U + 4*NG + i] = v2;
    wsf[W_U + 5*NG + i] = vop;
    wsf[W_U + 6*NG + i] = vr;
    wsf[W_U + 7*NG + i] = vg;
    wsf[W_U + 8*NG + i] = vb;
    wsf[W_U + 9*NG + i] = vd;
    wsf[W_KEY + i] = valid ? tz : INFINITY;

    out[O_RADII + i] = valid ? radf : 0.0f;
}

__global__ __launch_bounds__(1024) void k_sort(float* __restrict__ wsf, int* __restrict__ wsi)
{
    __shared__ float sk[NG];
    __shared__ int   si[NG];
    int t = threadIdx.x;
    for (int j = t; j < NG; j += 1024) { sk[j] = wsf[W_KEY + j]; si[j] = j; }

    for (unsigned k = 2; k <= (unsigned)NG; k <<= 1) {
        for (unsigned j = k >> 1; j > 0; j >>= 1) {
            __syncthreads();
            unsigned i = ((((unsigned)t) & ~(j - 1u)) << 1) | (((unsigned)t) & (j - 1u));
            unsigned p = i | j;
            bool up = (i & k) == 0;
            float ki = sk[i], kp = sk[p];
            int   ii = si[i], ip = si[p];
            bool gt = (ki > kp) || (ki == kp && ii > ip);
            if (gt == up) {
                sk[i] = kp; sk[p] = ki;
                si[i] = ip; si[p] = ii;
            }
        }
    }
    __syncthreads();

    for (int j = t; j < NG; j += 1024) {
        int oi = si[j];
        #pragma unroll
        for (int f = 0; f < 10; ++f)
            wsf[W_S + f*NG + j] = wsf[W_U + f*NG + oi];
        wsi[W_ORG + j] = oi;
    }
}

__global__ __launch_bounds__(PIXBLK) void k_rast(const float* __restrict__ wsf,
                                                 const int* __restrict__ sorg,
                                                 int* __restrict__ ntouch,
                                                 float* __restrict__ part)
{
    __shared__ float Lpx[SEGLEN], Lpy[SEGLEN], Lc0[SEGLEN], Lc1[SEGLEN], Lc2[SEGLEN];
    __shared__ float Lop[SEGLEN], Lr[SEGLEN], Lg[SEGLEN], Lb[SEGLEN], Ld[SEGLEN];
    __shared__ int cnt[SEGLEN];

    int tid = threadIdx.x;
    int pix = blockIdx.x * PIXBLK + tid;
    int s   = blockIdx.y;
    int gb  = s * SEGLEN;

    Lpx[tid] = wsf[W_S + 0*NG + gb + tid];
    Lpy[tid] = wsf[W_S + 1*NG + gb + tid];
    Lc0[tid] = wsf[W_S + 2*NG + gb + tid];
    Lc1[tid] = wsf[W_S + 3*NG + gb + tid];
    Lc2[tid] = wsf[W_S + 4*NG + gb + tid];
    Lop[tid] = wsf[W_S + 5*NG + gb + tid];
    Lr[tid]  = wsf[W_S + 6*NG + gb + tid];
    Lg[tid]  = wsf[W_S + 7*NG + gb + tid];
    Lb[tid]  = wsf[W_S + 8*NG + gb + tid];
    Ld[tid]  = wsf[W_S + 9*NG + gb + tid];
    cnt[tid] = 0;
    __syncthreads();

    float gx = (float)(pix % IMG_W);
    float gy = (float)(pix / IMG_W);

    float T = 1.0f, a0 = 0.0f, a1 = 0.0f, a2 = 0.0f, ad = 0.0f;

    for (int g = 0; g < SEGLEN; ++g) {
        float dx = Lpx[g] - gx;
        float dy = Lpy[g] - gy;
        float power = -0.5f * (Lc0[g]*dx*dx + Lc2[g]*dy*dy) - Lc1[g]*dx*dy;
        float alpha = fminf(0.99f, Lop[g] * expf(power));
        bool keep = (power <= 0.0f) && (alpha >= A_MIN);
        float a = keep ? alpha : 0.0f;
        float w = T * a;
        a0 += w * Lr[g];
        a1 += w * Lg[g];
        a2 += w * Lb[g];
        ad += w * Ld[g];
        T *= 1.0f - a;
        unsigned long long m = __ballot(keep);
        if ((tid & 63) == 0) atomicAdd(&cnt[g], (int)__popcll(m));
    }

    int idx = s * HW + pix;
    part[0*SEG*HW + idx] = T;
    part[1*SEG*HW + idx] = a0;
    part[2*SEG*HW + idx] = a1;
    part[3*SEG*HW + idx] = a2;
    part[4*SEG*HW + idx] = ad;

    __syncthreads();
    int c = cnt[tid];
    if (c > 0) atomicAdd(&ntouch[sorg[gb + tid]], c);
}

__global__ __launch_bounds__(PIXBLK) void k_comb(const float* __restrict__ part,
                                                 const int* __restrict__ ntouch,
                                                 const float* __restrict__ bg,
                                                 float* __restrict__ out)
{
    int tid = threadIdx.x;
    int pix = blockIdx.x * PIXBLK + tid;

    float T = 1.0f, c0 = 0.0f, c1 = 0.0f, c2 = 0.0f, d = 0.0f;
    #pragma unroll
    for (int s = 0; s < SEG; ++s) {
        int idx = s * HW + pix;
        float P = part[0*SEG*HW + idx];
        c0 += T * part[1*SEG*HW + idx];
        c1 += T * part[2*SEG*HW + idx];
        c2 += T * part[3*SEG*HW + idx];
        d  += T * part[4*SEG*HW + idx];
        T *= P;
    }

    out[O_COLOR + 0*HW + pix] = c0 + bg[0] * T;
    out[O_COLOR + 1*HW + pix] = c1 + bg[1] * T;
    out[O_COLOR + 2*HW + pix] = c2 + bg[2] * T;
    out[O_DEPTH + pix] = d;
    out[O_OPAC  + pix] = 1.0f - T;

    int gt = blockIdx.x * PIXBLK + tid;
    if (gt < NG) out[O_NT + gt] = (float)ntouch[gt];
}

extern "C" void kernel_launch(void* const* d_in, const int* in_sizes, int n_in,
                              void* d_out, int out_size, void* d_ws, size_t ws_size,
                              hipStream_t stream)
{
    const float* means3D = (const float*)d_in[0];
    // d_in[1] = means2D (unused)
    const float* opac    = (const float*)d_in[2];
    const float* cols    = (const float*)d_in[3];
    const float* scales  = (const float*)d_in[4];
    const float* rots    = (const float*)d_in[5];
    const float* bg      = (const float*)d_in[6];
    const float* vm      = (const float*)d_in[7];
    float* out = (float*)d_out;
    float* wsf = (float*)d_ws;
    int*   wsi = (int*)d_ws;

    hipLaunchKernelGGL(k_pre, dim3(NG / 256), dim3(256), 0, stream,
                       means3D, opac, cols, scales, rots, vm, wsf, wsi + W_NT, out);
    hipLaunchKernelGGL(k_sort, dim3(1), dim3(1024), 0, stream, wsf, wsi);
    hipLaunchKernelGGL(k_rast, dim3(NPIXBLK, SEG), dim3(PIXBLK), 0, stream,
                       wsf, wsi + W_ORG, wsi + W_NT, wsf + W_PART);
    hipLaunchKernelGGL(k_comb, dim3(NPIXBLK), dim3(PIXBLK), 0, stream,
                       wsf + W_PART, wsi + W_NT, bg, out);
}

// Round 2
// 78.054 us; speedup vs baseline: 1.7116x; 1.7116x over previous
//
#include <hip/hip_runtime.h>
#include <math.h>

namespace {

constexpr int NG     = 2048;
constexpr int IMG_H  = 160;
constexpr int IMG_W  = 224;
constexpr int HW     = IMG_H * IMG_W;   // 35840
constexpr int TS     = 8;               // tile size (8x8 px, 64 threads = 1 wave)
constexpr int TX     = IMG_W / TS;      // 28
constexpr int TYN    = IMG_H / TS;      // 20
constexpr int NTILE  = TX * TYN;        // 560

constexpr float TFX   = 0.5774f;
constexpr float TFY   = (float)(0.5774 * 160.0 / 224.0);
constexpr float FXC   = (float)(224.0 / (2.0 * 0.5774));
constexpr float FYC   = (float)(160.0 / (2.0 * (0.5774 * 160.0 / 224.0)));
constexpr float LIMX  = (float)(1.3 * 0.5774);
constexpr float LIMY  = (float)(1.3 * (0.5774 * 160.0 / 224.0));
constexpr float A_MIN = (float)(1.0 / 255.0);
constexpr float NEARP = 0.2f;
constexpr float LOWPASS = 0.3f;
constexpr float L2E   = 1.4426950408889634f;   // log2(e)
constexpr float LN2   = 0.6931471805599453f;
constexpr float L2_255 = 7.994353436858858f;   // log2(255)

// output float offsets (flat, in return order)
constexpr int O_COLOR = 0;
constexpr int O_RADII = 3 * HW;           // 107520
constexpr int O_DEPTH = O_RADII + NG;     // 109568
constexpr int O_OPAC  = O_DEPTH + HW;     // 145408
constexpr int O_NT    = O_OPAC + HW;      // 181248

// workspace float offsets
// AoS record (12 floats): [0]px [1]py [2]dxm [3]dym | [4]h0 [5]h1 [6]h2 [7]l2op | [8]r [9]g [10]b [11]dep
constexpr int W_U    = 0;          // unsorted AoS, NG*12 floats
constexpr int W_KEY  = 12 * NG;    // depth keys, NG floats
constexpr int W_S    = 13 * NG;    // sorted AoS, NG*12 floats
constexpr int W_ORG  = 25 * NG;    // int: original index per sorted slot

} // namespace

__global__ __launch_bounds__(256) void k_pre(const float* __restrict__ means3D,
                                             const float* __restrict__ opac,
                                             const float* __restrict__ cols,
                                             const float* __restrict__ scales,
                                             const float* __restrict__ rots,
                                             const float* __restrict__ vm,
                                             float* __restrict__ wsf,
                                             float* __restrict__ out)
{
    int i = blockIdx.x * blockDim.x + threadIdx.x;
    if (i >= NG) return;
    out[O_NT + i] = 0.0f;   // n_touched accumulator (float atomics, exact small ints)

    float R00 = vm[0], R01 = vm[1], R02 = vm[2],  T0 = vm[3];
    float R10 = vm[4], R11 = vm[5], R12 = vm[6],  T1 = vm[7];
    float R20 = vm[8], R21 = vm[9], R22 = vm[10], T2 = vm[11];

    float mx = means3D[3*i], my = means3D[3*i+1], mz = means3D[3*i+2];
    float tx = R00*mx + R01*my + R02*mz + T0;
    float ty = R10*mx + R11*my + R12*mz + T1;
    float tz = R20*mx + R21*my + R22*mz + T2;

    float txz = fminf(LIMX, fmaxf(-LIMX, tx / tz)) * tz;
    float tyz = fminf(LIMY, fmaxf(-LIMY, ty / tz)) * tz;

    float qw = rots[4*i], qx = rots[4*i+1], qy = rots[4*i+2], qz = rots[4*i+3];
    float qn = 1.0f / sqrtf(qw*qw + qx*qx + qy*qy + qz*qz);
    qw *= qn; qx *= qn; qy *= qn; qz *= qn;
    float r00 = 1.0f - 2.0f*(qy*qy + qz*qz), r01 = 2.0f*(qx*qy - qw*qz), r02 = 2.0f*(qx*qz + qw*qy);
    float r10 = 2.0f*(qx*qy + qw*qz), r11 = 1.0f - 2.0f*(qx*qx + qz*qz), r12 = 2.0f*(qy*qz - qw*qx);
    float r20 = 2.0f*(qx*qz - qw*qy), r21 = 2.0f*(qy*qz + qw*qx), r22 = 1.0f - 2.0f*(qx*qx + qy*qy);

    float s0 = scales[3*i];   s0 = s0 * s0;
    float s1 = scales[3*i+1]; s1 = s1 * s1;
    float s2 = scales[3*i+2]; s2 = s2 * s2;

    float S00 = r00*r00*s0 + r01*r01*s1 + r02*r02*s2;
    float S01 = r00*r10*s0 + r01*r11*s1 + r02*r12*s2;
    float S02 = r00*r20*s0 + r01*r21*s1 + r02*r22*s2;
    float S11 = r10*r10*s0 + r11*r11*s1 + r12*r12*s2;
    float S12 = r10*r20*s0 + r11*r21*s1 + r12*r22*s2;
    float S22 = r20*r20*s0 + r21*r21*s1 + r22*r22*s2;

    float j00 = FXC / tz;
    float j02 = -FXC * txz / (tz * tz);
    float j11 = FYC / tz;
    float j12 = -FYC * tyz / (tz * tz);

    float Tm00 = j00*R00 + j02*R20, Tm01 = j00*R01 + j02*R21, Tm02 = j00*R02 + j02*R22;
    float Tm10 = j11*R10 + j12*R20, Tm11 = j11*R11 + j12*R21, Tm12 = j11*R12 + j12*R22;

    float M00 = Tm00*S00 + Tm01*S01 + Tm02*S02;
    float M01 = Tm00*S01 + Tm01*S11 + Tm02*S12;
    float M02 = Tm00*S02 + Tm01*S12 + Tm02*S22;
    float M10 = Tm10*S00 + Tm11*S01 + Tm12*S02;
    float M11 = Tm10*S01 + Tm11*S11 + Tm12*S12;
    float M12 = Tm10*S02 + Tm11*S12 + Tm12*S22;

    float cov00 = M00*Tm00 + M01*Tm01 + M02*Tm02;
    float cov01 = M00*Tm10 + M01*Tm11 + M02*Tm12;
    float cov11 = M10*Tm10 + M11*Tm11 + M12*Tm12;

    float a = cov00 + LOWPASS;
    float b = cov01;
    float c = cov11 + LOWPASS;
    float det = a*c - b*b;
    float dinv = 1.0f / det;
    float con0 = c * dinv, con1 = -b * dinv, con2 = a * dinv;

    float mid  = 0.5f * (a + c);
    float lam1 = mid + sqrtf(fmaxf(0.1f, mid*mid - det));
    float radf = ceilf(3.0f * sqrtf(lam1));

    float px = ((tx / (tz * TFX) + 1.0f) * (float)IMG_W - 1.0f) * 0.5f;
    float py = ((ty / (tz * TFY) + 1.0f) * (float)IMG_H - 1.0f) * 0.5f;

    bool valid = (tz > NEARP) && (det > 0.0f) && (radf > 0.0f);

    float op   = opac[i];
    float l2op = log2f(op);
    // exact alpha-cutoff ellipse: alpha>=1/255 <=> power >= -ln(255*op); bbox half-widths
    float tlin = fmaxf(0.0f, (l2op + L2_255) * LN2);
    float dxm  = sqrtf(2.0f * tlin * a) * 1.001f + 0.1f;
    float dym  = sqrtf(2.0f * tlin * c) * 1.001f + 0.1f;

    float4 f0, f1, f2;
    if (valid) {
        f0 = make_float4(px, py, dxm, dym);
        f1 = make_float4(-0.5f*con0*L2E, -con1*L2E, -0.5f*con2*L2E, l2op);
        f2 = make_float4(cols[3*i], cols[3*i+1], cols[3*i+2], tz);
    } else {
        f0 = make_float4(1e9f, 1e9f, -1.0f, -1.0f);
        f1 = make_float4(0.0f, 0.0f, 0.0f, -1000.0f);
        f2 = make_float4(0.0f, 0.0f, 0.0f, 0.0f);
    }
    float4* dst = (float4*)&wsf[W_U + i*12];
    dst[0] = f0; dst[1] = f1; dst[2] = f2;
    wsf[W_KEY + i] = valid ? tz : INFINITY;
    out[O_RADII + i] = valid ? radf : 0.0f;
}

// stable parallel rank sort: rank[i] = #{j : key[j]<key[i] or (key[j]==key[i] and j<i)}
__global__ __launch_bounds__(256) void k_rank(float* __restrict__ wsf, int* __restrict__ wsi)
{
    __shared__ float sk[NG];
    int tid = threadIdx.x;
    int i = blockIdx.x * 256 + tid;
    for (int j = tid; j < NG; j += 256) sk[j] = wsf[W_KEY + j];
    __syncthreads();

    float ki = sk[i];
    int r = 0;
    const float4* k4 = (const float4*)sk;
    #pragma unroll 4
    for (int j = 0; j < NG/4; ++j) {
        float4 kk = k4[j];
        int jb = 4*j;
        r += (kk.x < ki || (kk.x == ki && (jb+0) < i)) ? 1 : 0;
        r += (kk.y < ki || (kk.y == ki && (jb+1) < i)) ? 1 : 0;
        r += (kk.z < ki || (kk.z == ki && (jb+2) < i)) ? 1 : 0;
        r += (kk.w < ki || (kk.w == ki && (jb+3) < i)) ? 1 : 0;
    }

    const float4* src = (const float4*)&wsf[W_U + i*12];
    float4 a0 = src[0], a1 = src[1], a2 = src[2];
    float4* dst = (float4*)&wsf[W_S + r*12];
    dst[0] = a0; dst[1] = a1; dst[2] = a2;
    wsi[W_ORG + r] = i;
}

__global__ __launch_bounds__(64) void k_rast(const float* __restrict__ wsf,
                                             const int* __restrict__ wsi,
                                             const float* __restrict__ bg,
                                             float* __restrict__ out)
{
    __shared__ int   Llist[NG];      // 8 KB, ordered tile list (sorted slot indices)
    __shared__ float Ls[64][12];     // 3 KB, staged chunk (AoS)
    __shared__ int   Lorg[64];

    int lane = threadIdx.x;
    int tx = blockIdx.x % TX, ty = blockIdx.x / TX;
    float xmin = (float)(tx * TS), xmax = xmin + (float)(TS - 1);
    float ymin = (float)(ty * TS), ymax = ymin + (float)(TS - 1);

    // ---- build ordered tile list (single wave: ballot-compact, depth order kept) ----
    int cnt = 0;
    float4 bb = *(const float4*)&wsf[W_S + lane*12];
    for (int base = 0; base < NG; base += 64) {
        float4 nxt;
        if (base + 64 < NG) nxt = *(const float4*)&wsf[W_S + (base + 64 + lane)*12];
        bool keep = (bb.z >= 0.0f)
                 && (bb.x - bb.z <= xmax) && (bb.x + bb.z >= xmin)
                 && (bb.y - bb.w <= ymax) && (bb.y + bb.w >= ymin);
        unsigned long long m = __ballot(keep);
        if (keep) Llist[cnt + __popcll(m & ((1ull << lane) - 1ull))] = base + lane;
        cnt += (int)__popcll(m);
        bb = nxt;
    }
    __syncthreads();

    // ---- composite: each lane owns one pixel of the 8x8 tile ----
    int px_i = tx * TS + (lane & 7);
    int py_i = ty * TS + (lane >> 3);
    float gx = (float)px_i, gy = (float)py_i;

    float T = 1.0f, C0 = 0.0f, C1 = 0.0f, C2 = 0.0f, D = 0.0f;

    for (int b2 = 0; b2 < cnt; b2 += 64) {
        int cl = min(64, cnt - b2);
        if (lane < cl) {
            int e = Llist[b2 + lane];
            const float4* s4 = (const float4*)&wsf[W_S + e*12];
            *(float4*)&Ls[lane][0] = s4[0];
            *(float4*)&Ls[lane][4] = s4[1];
            *(float4*)&Ls[lane][8] = s4[2];
            Lorg[lane] = wsi[W_ORG + e];
        }
        __syncthreads();
        #pragma unroll 2
        for (int g = 0; g < cl; ++g) {
            float4 f0 = *(const float4*)&Ls[g][0];   // px, py, (dxm, dym unused)
            float4 f1 = *(const float4*)&Ls[g][4];   // h0, h1, h2, l2op
            float4 f2 = *(const float4*)&Ls[g][8];   // r, g, b, dep
            float dx = f0.x - gx, dy = f0.y - gy;
            float p2 = f1.x*dx*dx + f1.y*dx*dy + f1.z*dy*dy;   // power*log2e (<=0 inside)
            float al = fminf(0.99f, exp2f(p2 + f1.w));
            bool keep = (p2 <= 0.0f) && (al >= A_MIN);
            float a = keep ? al : 0.0f;
            float w = T * a;
            C0 = fmaf(w, f2.x, C0);
            C1 = fmaf(w, f2.y, C1);
            C2 = fmaf(w, f2.z, C2);
            D  = fmaf(w, f2.w, D);
            T -= w;                                   // T *= (1-a)
            unsigned long long m = __ballot(keep);
            if (m != 0ull && lane == g) {
                atomicAdd(out + O_NT + Lorg[g], (float)__popcll(m));
            }
        }
        __syncthreads();
    }

    int pix = py_i * IMG_W + px_i;
    out[O_COLOR + 0*HW + pix] = C0 + bg[0] * T;
    out[O_COLOR + 1*HW + pix] = C1 + bg[1] * T;
    out[O_COLOR + 2*HW + pix] = C2 + bg[2] * T;
    out[O_DEPTH + pix] = D;
    out[O_OPAC  + pix] = 1.0f - T;
}

extern "C" void kernel_launch(void* const* d_in, const int* in_sizes, int n_in,
                              void* d_out, int out_size, void* d_ws, size_t ws_size,
                              hipStream_t stream)
{
    const float* means3D = (const float*)d_in[0];
    // d_in[1] = means2D (unused)
    const float* opac    = (const float*)d_in[2];
    const float* cols    = (const float*)d_in[3];
    const float* scales  = (const float*)d_in[4];
    const float* rots    = (const float*)d_in[5];
    const float* bg      = (const float*)d_in[6];
    const float* vm      = (const float*)d_in[7];
    float* out = (float*)d_out;
    float* wsf = (float*)d_ws;
    int*   wsi = (int*)d_ws;

    hipLaunchKernelGGL(k_pre, dim3(NG / 256), dim3(256), 0, stream,
                       means3D, opac, cols, scales, rots, vm, wsf, out);
    hipLaunchKernelGGL(k_rank, dim3(NG / 256), dim3(256), 0, stream, wsf, wsi);
    hipLaunchKernelGGL(k_rast, dim3(NTILE), dim3(64), 0, stream, wsf, wsi, bg, out);
}

// Round 3
// 36.805 us; speedup vs baseline: 3.6298x; 2.1207x over previous
//
#include <hip/hip_runtime.h>
#include <math.h>

namespace {

constexpr int NG     = 2048;
constexpr int IMG_H  = 160;
constexpr int IMG_W  = 224;
constexpr int HW     = IMG_H * IMG_W;   // 35840
constexpr int TS     = 8;               // tile size (8x8 px, 64 threads = 1 wave)
constexpr int TX     = IMG_W / TS;      // 28
constexpr int TYN    = IMG_H / TS;      // 20
constexpr int NTILE  = TX * TYN;        // 560

constexpr int TPG    = 16;              // k_rank: threads per gaussian
constexpr int SEGK   = NG / TPG;        // 128 keys per thread

constexpr float TFX   = 0.5774f;
constexpr float TFY   = (float)(0.5774 * 160.0 / 224.0);
constexpr float FXC   = (float)(224.0 / (2.0 * 0.5774));
constexpr float FYC   = (float)(160.0 / (2.0 * (0.5774 * 160.0 / 224.0)));
constexpr float LIMX  = (float)(1.3 * 0.5774);
constexpr float LIMY  = (float)(1.3 * (0.5774 * 160.0 / 224.0));
constexpr float A_MIN = (float)(1.0 / 255.0);
constexpr float NEARP = 0.2f;
constexpr float LOWPASS = 0.3f;
constexpr float L2E   = 1.4426950408889634f;   // log2(e)
constexpr float LN2   = 0.6931471805599453f;
constexpr float L2_255 = 7.994353436858858f;   // log2(255)

// output float offsets (flat, in return order)
constexpr int O_COLOR = 0;
constexpr int O_RADII = 3 * HW;           // 107520
constexpr int O_DEPTH = O_RADII + NG;     // 109568
constexpr int O_OPAC  = O_DEPTH + HW;     // 145408
constexpr int O_NT    = O_OPAC + HW;      // 181248

// workspace float offsets
// AoS record (12 floats): [0]px [1]py [2]dxm [3]dym | [4]h0 [5]h1 [6]h2 [7]l2op | [8]r [9]g [10]b [11]dep
constexpr int W_U    = 0;          // unsorted AoS, NG*12 floats
constexpr int W_KEY  = 12 * NG;    // depth keys, NG floats
constexpr int W_S    = 13 * NG;    // sorted AoS, NG*12 floats
constexpr int W_ORG  = 25 * NG;    // int: original index per sorted slot
constexpr int W_BB   = 26 * NG;    // sorted bbox SoA, NG float4s (coalesced scan)

} // namespace

__global__ __launch_bounds__(256) void k_pre(const float* __restrict__ means3D,
                                             const float* __restrict__ opac,
                                             const float* __restrict__ cols,
                                             const float* __restrict__ scales,
                                             const float* __restrict__ rots,
                                             const float* __restrict__ vm,
                                             float* __restrict__ wsf,
                                             float* __restrict__ out)
{
    int i = blockIdx.x * blockDim.x + threadIdx.x;
    if (i >= NG) return;
    out[O_NT + i] = 0.0f;   // n_touched accumulator (float atomics, exact small ints)

    float R00 = vm[0], R01 = vm[1], R02 = vm[2],  T0 = vm[3];
    float R10 = vm[4], R11 = vm[5], R12 = vm[6],  T1 = vm[7];
    float R20 = vm[8], R21 = vm[9], R22 = vm[10], T2 = vm[11];

    float mx = means3D[3*i], my = means3D[3*i+1], mz = means3D[3*i+2];
    float tx = R00*mx + R01*my + R02*mz + T0;
    float ty = R10*mx + R11*my + R12*mz + T1;
    float tz = R20*mx + R21*my + R22*mz + T2;

    float txz = fminf(LIMX, fmaxf(-LIMX, tx / tz)) * tz;
    float tyz = fminf(LIMY, fmaxf(-LIMY, ty / tz)) * tz;

    float qw = rots[4*i], qx = rots[4*i+1], qy = rots[4*i+2], qz = rots[4*i+3];
    float qn = 1.0f / sqrtf(qw*qw + qx*qx + qy*qy + qz*qz);
    qw *= qn; qx *= qn; qy *= qn; qz *= qn;
    float r00 = 1.0f - 2.0f*(qy*qy + qz*qz), r01 = 2.0f*(qx*qy - qw*qz), r02 = 2.0f*(qx*qz + qw*qy);
    float r10 = 2.0f*(qx*qy + qw*qz), r11 = 1.0f - 2.0f*(qx*qx + qz*qz), r12 = 2.0f*(qy*qz - qw*qx);
    float r20 = 2.0f*(qx*qz - qw*qy), r21 = 2.0f*(qy*qz + qw*qx), r22 = 1.0f - 2.0f*(qx*qx + qy*qy);

    float s0 = scales[3*i];   s0 = s0 * s0;
    float s1 = scales[3*i+1]; s1 = s1 * s1;
    float s2 = scales[3*i+2]; s2 = s2 * s2;

    float S00 = r00*r00*s0 + r01*r01*s1 + r02*r02*s2;
    float S01 = r00*r10*s0 + r01*r11*s1 + r02*r12*s2;
    float S02 = r00*r20*s0 + r01*r21*s1 + r02*r22*s2;
    float S11 = r10*r10*s0 + r11*r11*s1 + r12*r12*s2;
    float S12 = r10*r20*s0 + r11*r21*s1 + r12*r22*s2;
    float S22 = r20*r20*s0 + r21*r21*s1 + r22*r22*s2;

    float j00 = FXC / tz;
    float j02 = -FXC * txz / (tz * tz);
    float j11 = FYC / tz;
    float j12 = -FYC * tyz / (tz * tz);

    float Tm00 = j00*R00 + j02*R20, Tm01 = j00*R01 + j02*R21, Tm02 = j00*R02 + j02*R22;
    float Tm10 = j11*R10 + j12*R20, Tm11 = j11*R11 + j12*R21, Tm12 = j11*R12 + j12*R22;

    float M00 = Tm00*S00 + Tm01*S01 + Tm02*S02;
    float M01 = Tm00*S01 + Tm01*S11 + Tm02*S12;
    float M02 = Tm00*S02 + Tm01*S12 + Tm02*S22;
    float M10 = Tm10*S00 + Tm11*S01 + Tm12*S02;
    float M11 = Tm10*S01 + Tm11*S11 + Tm12*S12;
    float M12 = Tm10*S02 + Tm11*S12 + Tm12*S22;

    float cov00 = M00*Tm00 + M01*Tm01 + M02*Tm02;
    float cov01 = M00*Tm10 + M01*Tm11 + M02*Tm12;
    float cov11 = M10*Tm10 + M11*Tm11 + M12*Tm12;

    float a = cov00 + LOWPASS;
    float b = cov01;
    float c = cov11 + LOWPASS;
    float det = a*c - b*b;
    float dinv = 1.0f / det;
    float con0 = c * dinv, con1 = -b * dinv, con2 = a * dinv;

    float mid  = 0.5f * (a + c);
    float lam1 = mid + sqrtf(fmaxf(0.1f, mid*mid - det));
    float radf = ceilf(3.0f * sqrtf(lam1));

    float px = ((tx / (tz * TFX) + 1.0f) * (float)IMG_W - 1.0f) * 0.5f;
    float py = ((ty / (tz * TFY) + 1.0f) * (float)IMG_H - 1.0f) * 0.5f;

    bool valid = (tz > NEARP) && (det > 0.0f) && (radf > 0.0f);

    float op   = opac[i];
    float l2op = log2f(op);
    // exact alpha-cutoff ellipse: alpha>=1/255 <=> power >= -ln(255*op); bbox half-widths
    float tlin = fmaxf(0.0f, (l2op + L2_255) * LN2);
    float dxm  = sqrtf(2.0f * tlin * a) * 1.001f + 0.1f;
    float dym  = sqrtf(2.0f * tlin * c) * 1.001f + 0.1f;

    float4 f0, f1, f2;
    if (valid) {
        f0 = make_float4(px, py, dxm, dym);
        f1 = make_float4(-0.5f*con0*L2E, -con1*L2E, -0.5f*con2*L2E, l2op);
        f2 = make_float4(cols[3*i], cols[3*i+1], cols[3*i+2], tz);
    } else {
        f0 = make_float4(1e9f, 1e9f, -1.0f, -1.0f);
        f1 = make_float4(0.0f, 0.0f, 0.0f, -1000.0f);
        f2 = make_float4(0.0f, 0.0f, 0.0f, 0.0f);
    }
    float4* dst = (float4*)&wsf[W_U + i*12];
    dst[0] = f0; dst[1] = f1; dst[2] = f2;
    wsf[W_KEY + i] = valid ? tz : INFINITY;
    out[O_RADII + i] = valid ? radf : 0.0f;
}

// stable parallel rank sort, 16 threads per gaussian.
// rank[i] = #{j : key[j]<key[i] or (key[j]==key[i] and j<i)}
__global__ __launch_bounds__(256) void k_rank(float* __restrict__ wsf, int* __restrict__ wsi)
{
    __shared__ float sk[NG];
    int tid = threadIdx.x;
    float4* sk4 = (float4*)sk;
    const float4* gk4 = (const float4*)(wsf + W_KEY);
    sk4[tid]       = gk4[tid];
    sk4[tid + 256] = gk4[tid + 256];
    __syncthreads();

    int i = blockIdx.x * (256 / TPG) + (tid >> 4);
    int s = tid & (TPG - 1);
    float ki = sk[i];

    int r = 0;
    #pragma unroll 8
    for (int u = 0; u < SEGK / 4; ++u) {
        int j4 = (u + s) & (SEGK / 4 - 1);       // rotate per sub-thread: avoids 16-way bank conflict
        float4 kk = sk4[s * (SEGK / 4) + j4];
        int jb = s * SEGK + j4 * 4;
        r += (kk.x < ki || (kk.x == ki && (jb+0) < i)) ? 1 : 0;
        r += (kk.y < ki || (kk.y == ki && (jb+1) < i)) ? 1 : 0;
        r += (kk.z < ki || (kk.z == ki && (jb+2) < i)) ? 1 : 0;
        r += (kk.w < ki || (kk.w == ki && (jb+3) < i)) ? 1 : 0;
    }
    r += __shfl_xor(r, 1);
    r += __shfl_xor(r, 2);
    r += __shfl_xor(r, 4);
    r += __shfl_xor(r, 8);

    if (s == 0) {
        const float4* src = (const float4*)&wsf[W_U + i*12];
        float4 a0 = src[0], a1 = src[1], a2 = src[2];
        float4* dst = (float4*)&wsf[W_S + r*12];
        dst[0] = a0; dst[1] = a1; dst[2] = a2;
        *(float4*)&wsf[W_BB + r*4] = a0;
        wsi[W_ORG + r] = i;
    }
}

__global__ __launch_bounds__(64) void k_rast(const float* __restrict__ wsf,
                                             const int* __restrict__ wsi,
                                             const float* __restrict__ bg,
                                             float* __restrict__ out)
{
    __shared__ int   Llist[NG];      // 8 KB, ordered tile list (sorted slot indices)
    __shared__ int   Lcnt[NG];       // 8 KB, per-entry touched-pixel count
    __shared__ float Ls[64][12];     // 3 KB, staged chunk (AoS)

    int lane = threadIdx.x;
    int tx = blockIdx.x % TX, ty = blockIdx.x / TX;
    float xmin = (float)(tx * TS), xmax = xmin + (float)(TS - 1);
    float ymin = (float)(ty * TS), ymax = ymin + (float)(TS - 1);

    // ---- build ordered tile list (single wave: ballot-compact, depth order kept) ----
    int cnt = 0;
    float4 bb = *(const float4*)&wsf[W_BB + lane*4];
    for (int base = 0; base < NG; base += 64) {
        float4 nxt;
        if (base + 64 < NG) nxt = *(const float4*)&wsf[W_BB + (base + 64 + lane)*4];
        bool keep = (bb.z >= 0.0f)
                 && (bb.x - bb.z <= xmax) && (bb.x + bb.z >= xmin)
                 && (bb.y - bb.w <= ymax) && (bb.y + bb.w >= ymin);
        unsigned long long m = __ballot(keep);
        if (keep) Llist[cnt + __popcll(m & ((1ull << lane) - 1ull))] = base + lane;
        cnt += (int)__popcll(m);
        bb = nxt;
    }
    __syncthreads();

    // ---- composite: each lane owns one pixel of the 8x8 tile ----
    int px_i = tx * TS + (lane & 7);
    int py_i = ty * TS + (lane >> 3);
    float gx = (float)px_i, gy = (float)py_i;

    float T = 1.0f, C0 = 0.0f, C1 = 0.0f, C2 = 0.0f, D = 0.0f;

    for (int b2 = 0; b2 < cnt; b2 += 64) {
        int cl = min(64, cnt - b2);
        if (lane < cl) {
            int e = Llist[b2 + lane];
            const float4* s4 = (const float4*)&wsf[W_S + e*12];
            *(float4*)&Ls[lane][0] = s4[0];
            *(float4*)&Ls[lane][4] = s4[1];
            *(float4*)&Ls[lane][8] = s4[2];
        }
        __syncthreads();
        #pragma unroll 2
        for (int g = 0; g < cl; ++g) {
            float4 f0 = *(const float4*)&Ls[g][0];   // px, py, (dxm, dym unused)
            float4 f1 = *(const float4*)&Ls[g][4];   // h0, h1, h2, l2op
            float4 f2 = *(const float4*)&Ls[g][8];   // r, g, b, dep
            float dx = f0.x - gx, dy = f0.y - gy;
            float p2 = f1.x*dx*dx + f1.y*dx*dy + f1.z*dy*dy;   // power*log2e (<=0 inside)
            float al = fminf(0.99f, exp2f(p2 + f1.w));
            bool keep = (p2 <= 0.0f) && (al >= A_MIN);
            float a = keep ? al : 0.0f;
            float w = T * a;
            C0 = fmaf(w, f2.x, C0);
            C1 = fmaf(w, f2.y, C1);
            C2 = fmaf(w, f2.z, C2);
            D  = fmaf(w, f2.w, D);
            T -= w;                                   // T *= (1-a)
            unsigned long long m = __ballot(keep);
            if (lane == g) Lcnt[b2 + g] = (int)__popcll(m);
        }
        __syncthreads();
    }

    int pix = py_i * IMG_W + px_i;
    out[O_COLOR + 0*HW + pix] = C0 + bg[0] * T;
    out[O_COLOR + 1*HW + pix] = C1 + bg[1] * T;
    out[O_COLOR + 2*HW + pix] = C2 + bg[2] * T;
    out[O_DEPTH + pix] = D;
    out[O_OPAC  + pix] = 1.0f - T;

    // ---- batched n_touched flush ----
    for (int j = lane; j < cnt; j += 64) {
        int c = Lcnt[j];
        if (c > 0) atomicAdd(out + O_NT + wsi[W_ORG + Llist[j]], (float)c);
    }
}

extern "C" void kernel_launch(void* const* d_in, const int* in_sizes, int n_in,
                              void* d_out, int out_size, void* d_ws, size_t ws_size,
                              hipStream_t stream)
{
    const float* means3D = (const float*)d_in[0];
    // d_in[1] = means2D (unused)
    const float* opac    = (const float*)d_in[2];
    const float* cols    = (const float*)d_in[3];
    const float* scales  = (const float*)d_in[4];
    const float* rots    = (const float*)d_in[5];
    const float* bg      = (const float*)d_in[6];
    const float* vm      = (const float*)d_in[7];
    float* out = (float*)d_out;
    float* wsf = (float*)d_ws;
    int*   wsi = (int*)d_ws;

    hipLaunchKernelGGL(k_pre, dim3(NG / 256), dim3(256), 0, stream,
                       means3D, opac, cols, scales, rots, vm, wsf, out);
    hipLaunchKernelGGL(k_rank, dim3(NG / (256 / TPG)), dim3(256), 0, stream, wsf, wsi);
    hipLaunchKernelGGL(k_rast, dim3(NTILE), dim3(64), 0, stream, wsf, wsi, bg, out);
}

// Round 4
// 22.182 us; speedup vs baseline: 6.0227x; 1.6592x over previous
//
#include <hip/hip_runtime.h>
#include <math.h>

namespace {

constexpr int NG     = 2048;
constexpr int IMG_H  = 160;
constexpr int IMG_W  = 224;
constexpr int HW     = IMG_H * IMG_W;   // 35840
constexpr int TS     = 8;               // tile size (8x8 px, 64 threads = 1 wave)
constexpr int TX     = IMG_W / TS;      // 28
constexpr int TYN    = IMG_H / TS;      // 20
constexpr int NTILE  = TX * TYN;        // 560

constexpr int NSEG   = 4;               // depth segments for k_rast parallelism
constexpr int SEGS   = NG / NSEG;       // 512 slots per segment

constexpr int TPG    = 64;              // k_rank: threads per gaussian (full wave)
constexpr int SEGK   = NG / TPG;        // 32 keys per thread

constexpr float TFX   = 0.5774f;
constexpr float TFY   = (float)(0.5774 * 160.0 / 224.0);
constexpr float FXC   = (float)(224.0 / (2.0 * 0.5774));
constexpr float FYC   = (float)(160.0 / (2.0 * (0.5774 * 160.0 / 224.0)));
constexpr float LIMX  = (float)(1.3 * 0.5774);
constexpr float LIMY  = (float)(1.3 * (0.5774 * 160.0 / 224.0));
constexpr float A_MIN = (float)(1.0 / 255.0);
constexpr float NEARP = 0.2f;
constexpr float LOWPASS = 0.3f;
constexpr float L2E   = 1.4426950408889634f;   // log2(e)
constexpr float LN2   = 0.6931471805599453f;
constexpr float L2_255 = 7.994353436858858f;   // log2(255)

// output float offsets (flat, in return order)
constexpr int O_COLOR = 0;
constexpr int O_RADII = 3 * HW;           // 107520
constexpr int O_DEPTH = O_RADII + NG;     // 109568
constexpr int O_OPAC  = O_DEPTH + HW;     // 145408
constexpr int O_NT    = O_OPAC + HW;      // 181248

// workspace offsets (float/int units)
// AoS record (12 floats): [0]px [1]py [2]dxm [3]dym | [4]h0 [5]h1 [6]h2 [7]l2op | [8]r [9]g [10]b [11]dep
constexpr int W_U    = 0;          // unsorted AoS, NG*12 floats
constexpr int W_KEY  = 12 * NG;    // depth keys, NG floats
constexpr int W_UPB  = 13 * NG;    // unsorted packed tile bbox, NG uints
constexpr int W_S    = 14 * NG;    // sorted AoS, NG*12 floats
constexpr int W_ORG  = 26 * NG;    // int: original index per sorted slot
constexpr int W_PB   = 27 * NG;    // sorted packed tile bbox, NG uints
constexpr int W_PART = 28 * NG;    // NSEG*5*HW floats: per-seg T, Sc0, Sc1, Sc2, Sd

} // namespace

__global__ __launch_bounds__(256) void k_pre(const float* __restrict__ means3D,
                                             const float* __restrict__ opac,
                                             const float* __restrict__ cols,
                                             const float* __restrict__ scales,
                                             const float* __restrict__ rots,
                                             const float* __restrict__ vm,
                                             float* __restrict__ wsf,
                                             unsigned* __restrict__ wsu,
                                             float* __restrict__ out)
{
    int i = blockIdx.x * blockDim.x + threadIdx.x;
    if (i >= NG) return;
    out[O_NT + i] = 0.0f;   // n_touched accumulator (float atomics, exact small ints)

    float R00 = vm[0], R01 = vm[1], R02 = vm[2],  T0 = vm[3];
    float R10 = vm[4], R11 = vm[5], R12 = vm[6],  T1 = vm[7];
    float R20 = vm[8], R21 = vm[9], R22 = vm[10], T2 = vm[11];

    float mx = means3D[3*i], my = means3D[3*i+1], mz = means3D[3*i+2];
    float tx = R00*mx + R01*my + R02*mz + T0;
    float ty = R10*mx + R11*my + R12*mz + T1;
    float tz = R20*mx + R21*my + R22*mz + T2;

    float txz = fminf(LIMX, fmaxf(-LIMX, tx / tz)) * tz;
    float tyz = fminf(LIMY, fmaxf(-LIMY, ty / tz)) * tz;

    float qw = rots[4*i], qx = rots[4*i+1], qy = rots[4*i+2], qz = rots[4*i+3];
    float qn = 1.0f / sqrtf(qw*qw + qx*qx + qy*qy + qz*qz);
    qw *= qn; qx *= qn; qy *= qn; qz *= qn;
    float r00 = 1.0f - 2.0f*(qy*qy + qz*qz), r01 = 2.0f*(qx*qy - qw*qz), r02 = 2.0f*(qx*qz + qw*qy);
    float r10 = 2.0f*(qx*qy + qw*qz), r11 = 1.0f - 2.0f*(qx*qx + qz*qz), r12 = 2.0f*(qy*qz - qw*qx);
    float r20 = 2.0f*(qx*qz - qw*qy), r21 = 2.0f*(qy*qz + qw*qx), r22 = 1.0f - 2.0f*(qx*qx + qy*qy);

    float s0 = scales[3*i];   s0 = s0 * s0;
    float s1 = scales[3*i+1]; s1 = s1 * s1;
    float s2 = scales[3*i+2]; s2 = s2 * s2;

    float S00 = r00*r00*s0 + r01*r01*s1 + r02*r02*s2;
    float S01 = r00*r10*s0 + r01*r11*s1 + r02*r12*s2;
    float S02 = r00*r20*s0 + r01*r21*s1 + r02*r22*s2;
    float S11 = r10*r10*s0 + r11*r11*s1 + r12*r12*s2;
    float S12 = r10*r20*s0 + r11*r21*s1 + r12*r22*s2;
    float S22 = r20*r20*s0 + r21*r21*s1 + r22*r22*s2;

    float j00 = FXC / tz;
    float j02 = -FXC * txz / (tz * tz);
    float j11 = FYC / tz;
    float j12 = -FYC * tyz / (tz * tz);

    float Tm00 = j00*R00 + j02*R20, Tm01 = j00*R01 + j02*R21, Tm02 = j00*R02 + j02*R22;
    float Tm10 = j11*R10 + j12*R20, Tm11 = j11*R11 + j12*R21, Tm12 = j11*R12 + j12*R22;

    float M00 = Tm00*S00 + Tm01*S01 + Tm02*S02;
    float M01 = Tm00*S01 + Tm01*S11 + Tm02*S12;
    float M02 = Tm00*S02 + Tm01*S12 + Tm02*S22;
    float M10 = Tm10*S00 + Tm11*S01 + Tm12*S02;
    float M11 = Tm10*S01 + Tm11*S11 + Tm12*S12;
    float M12 = Tm10*S02 + Tm11*S12 + Tm12*S22;

    float cov00 = M00*Tm00 + M01*Tm01 + M02*Tm02;
    float cov01 = M00*Tm10 + M01*Tm11 + M02*Tm12;
    float cov11 = M10*Tm10 + M11*Tm11 + M12*Tm12;

    float a = cov00 + LOWPASS;
    float b = cov01;
    float c = cov11 + LOWPASS;
    float det = a*c - b*b;
    float dinv = 1.0f / det;
    float con0 = c * dinv, con1 = -b * dinv, con2 = a * dinv;

    float mid  = 0.5f * (a + c);
    float lam1 = mid + sqrtf(fmaxf(0.1f, mid*mid - det));
    float radf = ceilf(3.0f * sqrtf(lam1));

    float px = ((tx / (tz * TFX) + 1.0f) * (float)IMG_W - 1.0f) * 0.5f;
    float py = ((ty / (tz * TFY) + 1.0f) * (float)IMG_H - 1.0f) * 0.5f;

    bool valid = (tz > NEARP) && (det > 0.0f) && (radf > 0.0f);

    float op   = opac[i];
    float l2op = log2f(op);
    // exact alpha-cutoff ellipse: alpha>=1/255 <=> power >= -ln(255*op); bbox half-widths
    float tlin = fmaxf(0.0f, (l2op + L2_255) * LN2);
    float dxm  = sqrtf(2.0f * tlin * a) * 1.001f + 0.1f;
    float dym  = sqrtf(2.0f * tlin * c) * 1.001f + 0.1f;

    // packed conservative tile range (uchar4: tx0, ty0, tx1, ty1)
    int itx0 = (int)floorf((px - dxm) * (1.0f / TS));
    int itx1 = (int)floorf((px + dxm) * (1.0f / TS));
    int ity0 = (int)floorf((py - dym) * (1.0f / TS));
    int ity1 = (int)floorf((py + dym) * (1.0f / TS));
    unsigned pb;
    if (!valid || itx1 < 0 || ity1 < 0 || itx0 >= TX || ity0 >= TYN) {
        pb = 0xFFFFFFFFu;   // empty: tx0=255 never <= tx
    } else {
        unsigned a0 = (unsigned)max(itx0, 0);
        unsigned a1 = (unsigned)max(ity0, 0);
        unsigned a2 = (unsigned)min(itx1, TX - 1);
        unsigned a3 = (unsigned)min(ity1, TYN - 1);
        pb = a0 | (a1 << 8) | (a2 << 16) | (a3 << 24);
    }
    wsu[W_UPB + i] = pb;

    float4 f0, f1, f2;
    if (valid) {
        f0 = make_float4(px, py, dxm, dym);
        f1 = make_float4(-0.5f*con0*L2E, -con1*L2E, -0.5f*con2*L2E, l2op);
        f2 = make_float4(cols[3*i], cols[3*i+1], cols[3*i+2], tz);
    } else {
        f0 = make_float4(1e9f, 1e9f, -1.0f, -1.0f);
        f1 = make_float4(0.0f, 0.0f, 0.0f, -1000.0f);
        f2 = make_float4(0.0f, 0.0f, 0.0f, 0.0f);
    }
    float4* dst = (float4*)&wsf[W_U + i*12];
    dst[0] = f0; dst[1] = f1; dst[2] = f2;
    wsf[W_KEY + i] = valid ? tz : INFINITY;
    out[O_RADII + i] = valid ? radf : 0.0f;
}

// stable parallel rank sort, one wave (64 threads) per gaussian.
// rank[i] = #{j : key[j]<key[i] or (key[j]==key[i] and j<i)}
__global__ __launch_bounds__(256) void k_rank(float* __restrict__ wsf,
                                              int* __restrict__ wsi,
                                              unsigned* __restrict__ wsu)
{
    __shared__ float sk[NG];
    int tid = threadIdx.x;
    float4* sk4 = (float4*)sk;
    const float4* gk4 = (const float4*)(wsf + W_KEY);
    sk4[tid]       = gk4[tid];
    sk4[tid + 256] = gk4[tid + 256];
    __syncthreads();

    int i = blockIdx.x * (256 / TPG) + (tid >> 6);
    int s = tid & (TPG - 1);
    float ki = sk[i];

    int r = 0;
    #pragma unroll
    for (int u = 0; u < SEGK / 4; ++u) {
        int j4 = (u + s) & (SEGK / 4 - 1);       // rotate read phase per lane
        float4 kk = sk4[s * (SEGK / 4) + j4];
        int jb = s * SEGK + j4 * 4;
        r += (kk.x < ki || (kk.x == ki && (jb+0) < i)) ? 1 : 0;
        r += (kk.y < ki || (kk.y == ki && (jb+1) < i)) ? 1 : 0;
        r += (kk.z < ki || (kk.z == ki && (jb+2) < i)) ? 1 : 0;
        r += (kk.w < ki || (kk.w == ki && (jb+3) < i)) ? 1 : 0;
    }
    r += __shfl_xor(r, 1);
    r += __shfl_xor(r, 2);
    r += __shfl_xor(r, 4);
    r += __shfl_xor(r, 8);
    r += __shfl_xor(r, 16);
    r += __shfl_xor(r, 32);

    if (s == 0) {
        const float4* src = (const float4*)&wsf[W_U + i*12];
        float4 a0 = src[0], a1 = src[1], a2 = src[2];
        float4* dst = (float4*)&wsf[W_S + r*12];
        dst[0] = a0; dst[1] = a1; dst[2] = a2;
        wsu[W_PB + r] = wsu[W_UPB + i];
        wsi[W_ORG + r] = i;
    }
}

// one wave per (tile, depth-segment); composites SEGS sorted gaussians into partials
__global__ __launch_bounds__(64) void k_rast(const float* __restrict__ wsf,
                                             const int* __restrict__ wsi,
                                             const unsigned* __restrict__ wsu,
                                             float* __restrict__ part,
                                             float* __restrict__ out)
{
    __shared__ int   Llist[SEGS];    // 2 KB
    __shared__ int   Lcnt[SEGS];     // 2 KB
    __shared__ float Ls[64][12];     // 3 KB

    int lane = threadIdx.x;
    int tile = blockIdx.x;
    int seg  = blockIdx.y;
    int tx = tile % TX, ty = tile / TX;
    int base0 = seg * SEGS;

    // ---- scan this segment's packed tile ranges (8 coalesced uint loads) ----
    unsigned u[SEGS / 64];
    #pragma unroll
    for (int c = 0; c < SEGS / 64; ++c)
        u[c] = wsu[W_PB + base0 + c * 64 + lane];

    int cnt = 0;
    #pragma unroll
    for (int c = 0; c < SEGS / 64; ++c) {
        unsigned w = u[c];
        bool keep = ((w & 255u) <= (unsigned)tx) && ((unsigned)tx <= ((w >> 16) & 255u))
                 && (((w >> 8) & 255u) <= (unsigned)ty) && ((unsigned)ty <= (w >> 24));
        unsigned long long m = __ballot(keep);
        if (keep) Llist[cnt + __popcll(m & ((1ull << lane) - 1ull))] = base0 + c * 64 + lane;
        cnt += (int)__popcll(m);
    }
    __syncthreads();

    // ---- composite: each lane owns one pixel of the 8x8 tile ----
    int px_i = tx * TS + (lane & 7);
    int py_i = ty * TS + (lane >> 3);
    float gx = (float)px_i, gy = (float)py_i;

    float T = 1.0f, C0 = 0.0f, C1 = 0.0f, C2 = 0.0f, D = 0.0f;

    for (int b2 = 0; b2 < cnt; b2 += 64) {
        int cl = min(64, cnt - b2);
        if (lane < cl) {
            int e = Llist[b2 + lane];
            const float4* s4 = (const float4*)&wsf[W_S + e*12];
            *(float4*)&Ls[lane][0] = s4[0];
            *(float4*)&Ls[lane][4] = s4[1];
            *(float4*)&Ls[lane][8] = s4[2];
        }
        __syncthreads();
        #pragma unroll 2
        for (int g = 0; g < cl; ++g) {
            float4 f0 = *(const float4*)&Ls[g][0];   // px, py, (dxm, dym unused)
            float4 f1 = *(const float4*)&Ls[g][4];   // h0, h1, h2, l2op
            float4 f2 = *(const float4*)&Ls[g][8];   // r, g, b, dep
            float dx = f0.x - gx, dy = f0.y - gy;
            float p2 = f1.x*dx*dx + f1.y*dx*dy + f1.z*dy*dy;   // power*log2e (<=0 inside)
            float al = fminf(0.99f, exp2f(p2 + f1.w));
            bool keep = (p2 <= 0.0f) && (al >= A_MIN);
            float a = keep ? al : 0.0f;
            float w = T * a;
            C0 = fmaf(w, f2.x, C0);
            C1 = fmaf(w, f2.y, C1);
            C2 = fmaf(w, f2.z, C2);
            D  = fmaf(w, f2.w, D);
            T -= w;                                   // T *= (1-a)
            unsigned long long m = __ballot(keep);
            if (lane == g) Lcnt[b2 + g] = (int)__popcll(m);
        }
        __syncthreads();
    }

    int pix = py_i * IMG_W + px_i;
    float* p = part + seg * 5 * HW;
    p[0*HW + pix] = T;
    p[1*HW + pix] = C0;
    p[2*HW + pix] = C1;
    p[3*HW + pix] = C2;
    p[4*HW + pix] = D;

    // ---- batched n_touched flush (order-independent exact float atomics) ----
    for (int j = lane; j < cnt; j += 64) {
        int c = Lcnt[j];
        if (c > 0) atomicAdd(out + O_NT + wsi[W_ORG + Llist[j]], (float)c);
    }
}

__global__ __launch_bounds__(256) void k_comb(const float* __restrict__ part,
                                              const float* __restrict__ bg,
                                              float* __restrict__ out)
{
    int pix = blockIdx.x * 256 + threadIdx.x;
    if (pix >= HW) return;

    float T = 1.0f, C0 = 0.0f, C1 = 0.0f, C2 = 0.0f, D = 0.0f;
    #pragma unroll
    for (int s = 0; s < NSEG; ++s) {
        const float* p = part + s * 5 * HW;
        C0 = fmaf(T, p[1*HW + pix], C0);
        C1 = fmaf(T, p[2*HW + pix], C1);
        C2 = fmaf(T, p[3*HW + pix], C2);
        D  = fmaf(T, p[4*HW + pix], D);
        T *= p[0*HW + pix];
    }

    out[O_COLOR + 0*HW + pix] = C0 + bg[0] * T;
    out[O_COLOR + 1*HW + pix] = C1 + bg[1] * T;
    out[O_COLOR + 2*HW + pix] = C2 + bg[2] * T;
    out[O_DEPTH + pix] = D;
    out[O_OPAC  + pix] = 1.0f - T;
}

extern "C" void kernel_launch(void* const* d_in, const int* in_sizes, int n_in,
                              void* d_out, int out_size, void* d_ws, size_t ws_size,
                              hipStream_t stream)
{
    const float* means3D = (const float*)d_in[0];
    // d_in[1] = means2D (unused)
    const float* opac    = (const float*)d_in[2];
    const float* cols    = (const float*)d_in[3];
    const float* scales  = (const float*)d_in[4];
    const float* rots    = (const float*)d_in[5];
    const float* bg      = (const float*)d_in[6];
    const float* vm      = (const float*)d_in[7];
    float* out = (float*)d_out;
    float* wsf = (float*)d_ws;
    int*   wsi = (int*)d_ws;
    unsigned* wsu = (unsigned*)d_ws;

    hipLaunchKernelGGL(k_pre, dim3(NG / 256), dim3(256), 0, stream,
                       means3D, opac, cols, scales, rots, vm, wsf, wsu, out);
    hipLaunchKernelGGL(k_rank, dim3(NG / (256 / TPG)), dim3(256), 0, stream, wsf, wsi, wsu);
    hipLaunchKernelGGL(k_rast, dim3(NTILE, NSEG), dim3(64), 0, stream,
                       wsf, wsi, wsu, wsf + W_PART, out);
    hipLaunchKernelGGL(k_comb, dim3((HW + 255) / 256), dim3(256), 0, stream,
                       wsf + W_PART, bg, out);
}